// Round 7
// baseline (210.645 us; speedup 1.0000x reference)
//
#include <hip/hip_runtime.h>

// Problem constants: B=4, S=1024, H=1024, NH=16, DH=64, M=B*S=4096.

typedef __attribute__((ext_vector_type(8))) __bf16 bf16x8;
typedef __attribute__((ext_vector_type(4))) float f32x4;
typedef __attribute__((ext_vector_type(16))) float f32x16;
typedef __attribute__((ext_vector_type(8))) unsigned short u16x8;
typedef __attribute__((ext_vector_type(4))) unsigned short u16x4;

// workspace layout (ushort element offsets)
#define XQ_OFF 0u
#define XK_OFF 4194304u
#define XV_OFF 8388608u
#define WQ_OFF 12582912u
#define WK_OFF 13631488u
#define WV_OFF 14680064u
#define QP_OFF 15728640u
#define KP_OFF 19922944u
#define VT_OFF 24117248u   // V projection written DIRECTLY transposed: [(b*16+h)*64+dh][s]
// total = 28311552 ushorts = 54 MiB

__device__ __forceinline__ unsigned short f2bf(float f) {
  union { float f; unsigned int u; } c; c.f = f;
  return (unsigned short)((c.u + 0x7fffu + ((c.u >> 16) & 1u)) >> 16);  // RNE
}

// ---------------- fp32 -> bf16 conversion of inputs ----------------
__global__ __launch_bounds__(256) void cvt_kernel(
    const float* __restrict__ q, const float* __restrict__ k, const float* __restrict__ v,
    const float* __restrict__ wq, const float* __restrict__ wk, const float* __restrict__ wv,
    unsigned short* __restrict__ ws) {
  const int z = blockIdx.y;
  const float* src; unsigned short* dst; int n;
  switch (z) {
    case 0: src = q;  dst = ws + XQ_OFF; n = 4194304; break;
    case 1: src = k;  dst = ws + XK_OFF; n = 4194304; break;
    case 2: src = v;  dst = ws + XV_OFF; n = 4194304; break;
    case 3: src = wq; dst = ws + WQ_OFF; n = 1048576; break;
    case 4: src = wk; dst = ws + WK_OFF; n = 1048576; break;
    default: src = wv; dst = ws + WV_OFF; n = 1048576; break;
  }
  const int i8 = (blockIdx.x * 256 + threadIdx.x) * 8;
  if (i8 >= n) return;
  const float4 f0 = *(const float4*)(src + i8);
  const float4 f1 = *(const float4*)(src + i8 + 4);
  u16x8 r;
  r[0] = f2bf(f0.x); r[1] = f2bf(f0.y); r[2] = f2bf(f0.z); r[3] = f2bf(f0.w);
  r[4] = f2bf(f1.x); r[5] = f2bf(f1.y); r[6] = f2bf(f1.z); r[7] = f2bf(f1.w);
  *(u16x8*)(dst + i8) = r;
}

// ---------------- fused projection GEMMs: P = relu(X @ W^T + b), bf16 out ----------------
// r7: 32x32x16 MFMA (8 instr/iter vs 16; +15% MFMA ceiling per m119) + strength-reduced
// staging pointers (4 running ptrs += 32/iter, replaces ~21 v_lshl_add_u64/iter of m97-style
// addr recompute). As/Bs chunk-XOR-swizzled (pch = lch ^ (row&3)) so DMA staging stays
// lane-contiguous AND 32-row fragment reads stay at the uniform 8-access/bank minimum.
// C/D layout (m74/m101-verified): col=lane&31, row=(reg&3)+8*(reg>>2)+4*(lane>>5).
__global__ __launch_bounds__(256) void proj_gemm(
    unsigned short* __restrict__ ws,
    const float* __restrict__ bq, const float* __restrict__ bk, const float* __restrict__ bv) {
  __shared__ unsigned short smem[18432];  // k-loop: As[0:4096], Bs[4096:8192]; epilogue: Tw[w*4608]
  unsigned short* As = smem;
  unsigned short* Bs = smem + 4096;
  const int z = blockIdx.z;
  const unsigned short* X = ws + (z == 0 ? XQ_OFF : z == 1 ? XK_OFF : XV_OFF);
  const unsigned short* W = ws + (z == 0 ? WQ_OFF : z == 1 ? WK_OFF : WV_OFF);
  unsigned short* P = ws + (z == 0 ? QP_OFF : z == 1 ? KP_OFF : VT_OFF);
  const float* bias = z == 0 ? bq : z == 1 ? bk : bv;

  const int tid  = threadIdx.x;
  const int lane = tid & 63;
  const int w    = tid >> 6;
  const int l31  = lane & 31;
  const int g    = lane >> 5;       // k-group within 32x32x16 operand
  const int wr = w >> 1, wc = w & 1;
  const int m0 = blockIdx.y * 128;
  const int n0 = blockIdx.x * 128;

  f32x16 acc[2][2];
#pragma unroll
  for (int i = 0; i < 2; ++i)
#pragma unroll
    for (int j = 0; j < 2; ++j)
#pragma unroll
      for (int r = 0; r < 16; ++r) acc[i][j][r] = 0.f;

  // staging: chunk c -> row c>>2, physical chunk c&3 holds LOGICAL chunk (c&3)^(row&3)
  const int c0 = tid, c1 = 256 + tid;
  const int row0 = c0 >> 2, kc0 = (((c0 & 3) ^ (row0 & 3)) * 8);
  const int row1 = c1 >> 2, kc1 = (((c1 & 3) ^ (row1 & 3)) * 8);
  const unsigned short* gA0 = X + (size_t)(m0 + row0) * 1024 + kc0;
  const unsigned short* gA1 = X + (size_t)(m0 + row1) * 1024 + kc1;
  const unsigned short* gB0 = W + (size_t)(n0 + row0) * 1024 + kc0;
  const unsigned short* gB1 = W + (size_t)(n0 + row1) * 1024 + kc1;
  unsigned short* lA0 = &As[(w * 64) * 8];
  unsigned short* lA1 = &As[(256 + w * 64) * 8];
  unsigned short* lB0 = &Bs[(w * 64) * 8];
  unsigned short* lB1 = &Bs[(256 + w * 64) * 8];

  for (int kt = 0; kt < 32; ++kt) {
    __builtin_amdgcn_global_load_lds((const __attribute__((address_space(1))) void*)gA0,
                                     (__attribute__((address_space(3))) void*)lA0, 16, 0, 0);
    __builtin_amdgcn_global_load_lds((const __attribute__((address_space(1))) void*)gB0,
                                     (__attribute__((address_space(3))) void*)lB0, 16, 0, 0);
    __builtin_amdgcn_global_load_lds((const __attribute__((address_space(1))) void*)gA1,
                                     (__attribute__((address_space(3))) void*)lA1, 16, 0, 0);
    __builtin_amdgcn_global_load_lds((const __attribute__((address_space(1))) void*)gB1,
                                     (__attribute__((address_space(3))) void*)lB1, 16, 0, 0);
    gA0 += 32; gA1 += 32; gB0 += 32; gB1 += 32;
    __syncthreads();
    // fragments: A[m=l31][k=g*8+j] at row wr*64+mt*32+l31, logical chunk kk*2+g
    bf16x8 af[2][2], bfv[2][2];
#pragma unroll
    for (int mt = 0; mt < 2; ++mt)
#pragma unroll
      for (int kk = 0; kk < 2; ++kk) {
        const int ra = wr * 64 + mt * 32 + l31;
        af[mt][kk] = *(const bf16x8*)&As[ra * 32 + (((kk * 2 + g) ^ (ra & 3)) * 8)];
      }
#pragma unroll
    for (int nt = 0; nt < 2; ++nt)
#pragma unroll
      for (int kk = 0; kk < 2; ++kk) {
        const int rb = wc * 64 + nt * 32 + l31;
        bfv[nt][kk] = *(const bf16x8*)&Bs[rb * 32 + (((kk * 2 + g) ^ (rb & 3)) * 8)];
      }
#pragma unroll
    for (int mt = 0; mt < 2; ++mt)
#pragma unroll
      for (int nt = 0; nt < 2; ++nt)
#pragma unroll
        for (int kk = 0; kk < 2; ++kk)
          acc[mt][nt] = __builtin_amdgcn_mfma_f32_32x32x16_bf16(af[mt][kk], bfv[nt][kk],
                                                                acc[mt][nt], 0, 0, 0);
    __syncthreads();
  }

  // ---- epilogue: per-wave 64x64 repack through LDS (As/Bs dead after last barrier) ----
  unsigned short* Tw = smem + w * 4608;  // 64 * 72
  if (z != 2) {
#pragma unroll
    for (int mt = 0; mt < 2; ++mt)
#pragma unroll
      for (int nt = 0; nt < 2; ++nt) {
        const float bvv = bias[n0 + wc * 64 + nt * 32 + l31];
#pragma unroll
        for (int reg = 0; reg < 16; ++reg) {
          const int rloc = (reg & 3) + 8 * (reg >> 2) + 4 * g;
          float v = acc[mt][nt][reg] + bvv;
          v = v > 0.f ? v : 0.f;
          Tw[(mt * 32 + rloc) * 72 + nt * 32 + l31] = f2bf(v);
        }
      }
    const int row0g = m0 + wr * 64;
    const int colb  = n0 + wc * 64;
#pragma unroll
    for (int i = 0; i < 8; ++i) {
      const int rr = i * 8 + (lane >> 3);
      const int cc = (lane & 7) * 8;
      *(u16x8*)&P[(size_t)(row0g + rr) * 1024 + colb + cc] = *(const u16x8*)&Tw[rr * 72 + cc];
    }
  } else {
    // transposed out (VT[(b*16+h)*64+dh][s]). Tw[col][row]: b64 in (4 consecutive rows/reg-quad).
#pragma unroll
    for (int mt = 0; mt < 2; ++mt)
#pragma unroll
      for (int nt = 0; nt < 2; ++nt) {
        const float bvv = bias[n0 + wc * 64 + nt * 32 + l31];
#pragma unroll
        for (int rq = 0; rq < 4; ++rq) {
          u16x4 pk;
#pragma unroll
          for (int r = 0; r < 4; ++r) {
            float v = acc[mt][nt][rq * 4 + r] + bvv;
            v = v > 0.f ? v : 0.f;
            pk[r] = f2bf(v);
          }
          *(u16x4*)&Tw[(nt * 32 + l31) * 72 + mt * 32 + rq * 8 + g * 4] = pk;
        }
      }
    const int h2 = (n0 >> 6) + wc;        // head index
    const int bb = m0 >> 10;              // batch
    const int s0 = (m0 & 1023) + wr * 64; // s within batch
#pragma unroll
    for (int i = 0; i < 8; ++i) {
      const int rr = i * 8 + (lane >> 3);  // dh
      const int cc = (lane & 7) * 8;       // s chunk
      *(u16x8*)&P[((size_t)(bb * 16 + h2) * 64 + rr) * 1024 + s0 + cc] =
          *(const u16x8*)&Tw[rr * 72 + cc];
    }
  }
}

// ---------------- fused flash attention + mask + residual (unchanged from r6) ----------------
__global__ __launch_bounds__(256) void attn_kernel(
    const unsigned short* __restrict__ QP, const unsigned short* __restrict__ KP,
    const unsigned short* __restrict__ VT, const float* __restrict__ masks,
    const float* __restrict__ query, float* __restrict__ out) {
  __shared__ unsigned short Kt[64 * 64];     // [key][dh], chunk-swizzled, no pad (DMA dest)
  __shared__ unsigned short Vt[64 * 64];     // [dh][key], chunk-swizzled, no pad (DMA dest)
  __shared__ unsigned short Pl[4][32 * 72];  // per-wave P [q][key], padded
  const int tid  = threadIdx.x;
  const int lane = tid & 63;
  const int w    = tid >> 6;
  const int quad = lane >> 4;
  const int l15  = lane & 15;
  const int b = blockIdx.z, h = blockIdx.y;
  const int q0w = blockIdx.x * 128 + w * 32;
  const size_t base = (size_t)b * 1024 * 1024;
  const int bh = b * 16 + h;

  bf16x8 qf[2][2];
#pragma unroll
  for (int mt = 0; mt < 2; ++mt)
#pragma unroll
    for (int kk = 0; kk < 2; ++kk)
      qf[mt][kk] = *(const bf16x8*)&QP[base + (size_t)(q0w + mt * 16 + l15) * 1024 +
                                       h * 64 + kk * 32 + quad * 8];

  f32x4 o[2][4];
  float lsum[2] = {0.f, 0.f};
#pragma unroll
  for (int mt = 0; mt < 2; ++mt)
#pragma unroll
    for (int nd = 0; nd < 4; ++nd) o[mt][nd] = f32x4{0.f, 0.f, 0.f, 0.f};

  const int r_st = lane >> 3;
  const int pc   = lane & 7;
  const int swz  = l15 & 7;
  const float cvt = 0.18033688011112042f;  // (1/sqrt(64)) * log2(e)

  for (int kb = 0; kb < 16; ++kb) {
    const int key0 = kb * 64;
#pragma unroll
    for (int t = 0; t < 2; ++t) {
      const int rowk = (w * 2 + t) * 8 + r_st;
      const int lc   = pc ^ (rowk & 7);
      const unsigned short* gk = &KP[base + (size_t)(key0 + rowk) * 1024 + h * 64 + lc * 8];
      const unsigned short* gv = &VT[((size_t)bh * 64 + rowk) * 1024 + key0 + lc * 8];
      __builtin_amdgcn_global_load_lds((const __attribute__((address_space(1))) void*)gk,
                                       (__attribute__((address_space(3))) void*)&Kt[(w * 2 + t) * 512],
                                       16, 0, 0);
      __builtin_amdgcn_global_load_lds((const __attribute__((address_space(1))) void*)gv,
                                       (__attribute__((address_space(3))) void*)&Vt[(w * 2 + t) * 512],
                                       16, 0, 0);
    }
    __syncthreads();

    bf16x8 kf[2][4];
#pragma unroll
    for (int kk = 0; kk < 2; ++kk)
#pragma unroll
      for (int ni = 0; ni < 4; ++ni)
        kf[kk][ni] = *(const bf16x8*)&Kt[(ni * 16 + l15) * 64 + ((kk * 4 + quad) ^ swz) * 8];

#pragma unroll
    for (int mt = 0; mt < 2; ++mt) {
      f32x4 st[4];
#pragma unroll
      for (int ni = 0; ni < 4; ++ni) st[ni] = f32x4{0.f, 0.f, 0.f, 0.f};
#pragma unroll
      for (int kk = 0; kk < 2; ++kk)
#pragma unroll
        for (int ni = 0; ni < 4; ++ni)
          st[ni] = __builtin_amdgcn_mfma_f32_16x16x32_bf16(kf[kk][ni], qf[mt][kk], st[ni], 0, 0, 0);
      float ls = 0.f;
#pragma unroll
      for (int ni = 0; ni < 4; ++ni) {
        u16x4 pk;
#pragma unroll
        for (int r = 0; r < 4; ++r) {
          const float p = exp2f(st[ni][r] * cvt - 8.0f);  // fixed shift, exact (scores>=0)
          ls += p;
          pk[r] = f2bf(p);
        }
        *(u16x4*)&Pl[w][(mt * 16 + l15) * 72 + ni * 16 + quad * 4] = pk;
      }
      lsum[mt] += ls;
    }

#pragma unroll
    for (int kk = 0; kk < 2; ++kk) {
      bf16x8 pa[2];
#pragma unroll
      for (int mt = 0; mt < 2; ++mt)
        pa[mt] = *(const bf16x8*)&Pl[w][(mt * 16 + l15) * 72 + kk * 32 + quad * 8];
#pragma unroll
      for (int nd = 0; nd < 4; ++nd) {
        bf16x8 vf = *(const bf16x8*)&Vt[(nd * 16 + l15) * 64 + ((kk * 4 + quad) ^ swz) * 8];
#pragma unroll
        for (int mt = 0; mt < 2; ++mt)
          o[mt][nd] = __builtin_amdgcn_mfma_f32_16x16x32_bf16(pa[mt], vf, o[mt][nd], 0, 0, 0);
      }
    }
    __syncthreads();
  }

#pragma unroll
  for (int mt = 0; mt < 2; ++mt) {
    lsum[mt] += __shfl_xor(lsum[mt], 16);
    lsum[mt] += __shfl_xor(lsum[mt], 32);
  }

#pragma unroll
  for (int mt = 0; mt < 2; ++mt)
#pragma unroll
    for (int r = 0; r < 4; ++r) {
      const int rq = quad * 4 + r;
      const float ls = __shfl(lsum[mt], (lane & 48) | rq);
      const int row = q0w + mt * 16 + rq;
      const float scale = masks[b * 1024 + row] / ls;
#pragma unroll
      for (int nd = 0; nd < 4; ++nd) {
        const int col = h * 64 + nd * 16 + l15;
        const size_t gi = base + (size_t)row * 1024 + col;
        out[gi] = o[mt][nd][r] * scale + query[gi];
      }
    }
}

extern "C" void kernel_launch(void* const* d_in, const int* in_sizes, int n_in,
                              void* d_out, int out_size, void* d_ws, size_t ws_size,
                              hipStream_t stream) {
  const float* q     = (const float*)d_in[0];
  const float* k     = (const float*)d_in[1];
  const float* v     = (const float*)d_in[2];
  const float* masks = (const float*)d_in[3];
  const float* Wq    = (const float*)d_in[4];
  const float* bq    = (const float*)d_in[5];
  const float* Wk    = (const float*)d_in[6];
  const float* bk    = (const float*)d_in[7];
  const float* Wv    = (const float*)d_in[8];
  const float* bv    = (const float*)d_in[9];
  float* out = (float*)d_out;
  unsigned short* ws = (unsigned short*)d_ws;

  cvt_kernel<<<dim3(2048, 6), 256, 0, stream>>>(q, k, v, Wq, Wk, Wv, ws);
  proj_gemm<<<dim3(8, 32, 3), 256, 0, stream>>>(ws, bq, bk, bv);
  attn_kernel<<<dim3(8, 16, 4), 256, 0, stream>>>(ws + QP_OFF, ws + KP_OFF, ws + VT_OFF,
                                                  masks, q, out);
}

// Round 8
// 198.603 us; speedup vs baseline: 1.0606x; 1.0606x over previous
//
#include <hip/hip_runtime.h>

// Problem constants: B=4, S=1024, H=1024, NH=16, DH=64, M=B*S=4096.

typedef __attribute__((ext_vector_type(8))) __bf16 bf16x8;
typedef __attribute__((ext_vector_type(4))) float f32x4;
typedef __attribute__((ext_vector_type(16))) float f32x16;
typedef __attribute__((ext_vector_type(8))) unsigned short u16x8;
typedef __attribute__((ext_vector_type(4))) unsigned short u16x4;

// workspace layout (ushort element offsets)
#define XQ_OFF 0u
#define XK_OFF 4194304u
#define XV_OFF 8388608u
#define WQ_OFF 12582912u
#define WK_OFF 13631488u
#define WV_OFF 14680064u
#define QP_OFF 15728640u
#define KP_OFF 19922944u
#define VT_OFF 24117248u   // V projection written DIRECTLY transposed: [(b*16+h)*64+dh][s]
// total = 28311552 ushorts = 54 MiB

__device__ __forceinline__ unsigned short f2bf(float f) {
  union { float f; unsigned int u; } c; c.f = f;
  return (unsigned short)((c.u + 0x7fffu + ((c.u >> 16) & 1u)) >> 16);  // RNE
}

// ---------------- fp32 -> bf16 conversion of inputs ----------------
__global__ __launch_bounds__(256) void cvt_kernel(
    const float* __restrict__ q, const float* __restrict__ k, const float* __restrict__ v,
    const float* __restrict__ wq, const float* __restrict__ wk, const float* __restrict__ wv,
    unsigned short* __restrict__ ws) {
  const int z = blockIdx.y;
  const float* src; unsigned short* dst; int n;
  switch (z) {
    case 0: src = q;  dst = ws + XQ_OFF; n = 4194304; break;
    case 1: src = k;  dst = ws + XK_OFF; n = 4194304; break;
    case 2: src = v;  dst = ws + XV_OFF; n = 4194304; break;
    case 3: src = wq; dst = ws + WQ_OFF; n = 1048576; break;
    case 4: src = wk; dst = ws + WK_OFF; n = 1048576; break;
    default: src = wv; dst = ws + WV_OFF; n = 1048576; break;
  }
  const int i8 = (blockIdx.x * 256 + threadIdx.x) * 8;
  if (i8 >= n) return;
  const float4 f0 = *(const float4*)(src + i8);
  const float4 f1 = *(const float4*)(src + i8 + 4);
  u16x8 r;
  r[0] = f2bf(f0.x); r[1] = f2bf(f0.y); r[2] = f2bf(f0.z); r[3] = f2bf(f0.w);
  r[4] = f2bf(f1.x); r[5] = f2bf(f1.y); r[6] = f2bf(f1.z); r[7] = f2bf(f1.w);
  *(u16x8*)(dst + i8) = r;
}

// ---------------- fused projection GEMMs: P = relu(X @ W^T + b), bf16 out ----------------
// r8: DOUBLE-BUFFERED staging (DMA for tile k+1 issued before computing tile k, so the
// vmcnt(0) drain at the next barrier lands after a full compute phase — r7 exposed naked
// DMA latency every iter) + XCD-aware block remap (per-XCD set: 4 X-tiles + all W = 3MB
// fits the 4MB XCD L2; cuts the 3.4x cross-XCD HBM over-fetch).
// 32x32x16 MFMA; XOR-chunk swizzle (uniform 8-access/bank, audit r7);
// C/D layout (m74/m101-verified): col=lane&31, row=(reg&3)+8*(reg>>2)+4*(lane>>5).
__global__ __launch_bounds__(256) void proj_gemm(
    unsigned short* __restrict__ ws,
    const float* __restrict__ bq, const float* __restrict__ bk, const float* __restrict__ bv) {
  __shared__ unsigned short smem[18432];  // buf0: As[0:4096]+Bs[4096:8192]; buf1: +8192; Tw overlays
  const int z = blockIdx.z;
  const unsigned short* X = ws + (z == 0 ? XQ_OFF : z == 1 ? XK_OFF : XV_OFF);
  const unsigned short* W = ws + (z == 0 ? WQ_OFF : z == 1 ? WK_OFF : WV_OFF);
  unsigned short* P = ws + (z == 0 ? QP_OFF : z == 1 ? KP_OFF : VT_OFF);
  const float* bias = z == 0 ? bq : z == 1 ? bk : bv;

  const int tid  = threadIdx.x;
  const int lane = tid & 63;
  const int w    = tid >> 6;
  const int l31  = lane & 31;
  const int g    = lane >> 5;       // k-group within 32x32x16 operand
  const int wr = w >> 1, wc = w & 1;

  // XCD-aware remap: XCD j (lin%8 round-robin) gets m-tiles 4j..4j+3 x all 8 n-tiles.
  const int lin = blockIdx.x + 8 * blockIdx.y;   // 0..255
  const int xcd = lin & 7;
  const int idx = lin >> 3;                      // 0..31
  const int m0 = (xcd * 4 + (idx >> 3)) * 128;
  const int n0 = (idx & 7) * 128;

  f32x16 acc[2][2];
#pragma unroll
  for (int i = 0; i < 2; ++i)
#pragma unroll
    for (int j = 0; j < 2; ++j)
#pragma unroll
      for (int r = 0; r < 16; ++r) acc[i][j][r] = 0.f;

  // staging addresses: chunk c -> row c>>2, physical chunk c&3 holds LOGICAL chunk (c&3)^(row&3)
  const int c1 = 256 + tid;
  const int row0 = tid >> 2, kc0 = (((tid & 3) ^ (row0 & 3)) * 8);
  const int row1 = c1 >> 2,  kc1 = (((c1 & 3) ^ (row1 & 3)) * 8);
  const unsigned short* gA0 = X + (size_t)(m0 + row0) * 1024 + kc0;
  const unsigned short* gA1 = X + (size_t)(m0 + row1) * 1024 + kc1;
  const unsigned short* gB0 = W + (size_t)(n0 + row0) * 1024 + kc0;
  const unsigned short* gB1 = W + (size_t)(n0 + row1) * 1024 + kc1;
  const int d0 = w * 512, d1 = 2048 + w * 512;   // per-wave LDS dest offsets

  auto stage = [&](int buf) {  // issue 4 DMA for the next tile into buf, advance ptrs
    unsigned short* Ab = smem + buf * 8192;
    unsigned short* Bb = Ab + 4096;
    __builtin_amdgcn_global_load_lds((const __attribute__((address_space(1))) void*)gA0,
                                     (__attribute__((address_space(3))) void*)(Ab + d0), 16, 0, 0);
    __builtin_amdgcn_global_load_lds((const __attribute__((address_space(1))) void*)gB0,
                                     (__attribute__((address_space(3))) void*)(Bb + d0), 16, 0, 0);
    __builtin_amdgcn_global_load_lds((const __attribute__((address_space(1))) void*)gA1,
                                     (__attribute__((address_space(3))) void*)(Ab + d1), 16, 0, 0);
    __builtin_amdgcn_global_load_lds((const __attribute__((address_space(1))) void*)gB1,
                                     (__attribute__((address_space(3))) void*)(Bb + d1), 16, 0, 0);
    gA0 += 32; gA1 += 32; gB0 += 32; gB1 += 32;
  };
  auto compute = [&](int buf) {
    const unsigned short* Ab = smem + buf * 8192;
    const unsigned short* Bb = Ab + 4096;
    bf16x8 af[2][2], bfv[2][2];
#pragma unroll
    for (int mt = 0; mt < 2; ++mt)
#pragma unroll
      for (int kk = 0; kk < 2; ++kk) {
        const int ra = wr * 64 + mt * 32 + l31;
        af[mt][kk] = *(const bf16x8*)&Ab[ra * 32 + (((kk * 2 + g) ^ (ra & 3)) * 8)];
      }
#pragma unroll
    for (int nt = 0; nt < 2; ++nt)
#pragma unroll
      for (int kk = 0; kk < 2; ++kk) {
        const int rb = wc * 64 + nt * 32 + l31;
        bfv[nt][kk] = *(const bf16x8*)&Bb[rb * 32 + (((kk * 2 + g) ^ (rb & 3)) * 8)];
      }
#pragma unroll
    for (int mt = 0; mt < 2; ++mt)
#pragma unroll
      for (int nt = 0; nt < 2; ++nt)
#pragma unroll
        for (int kk = 0; kk < 2; ++kk)
          acc[mt][nt] = __builtin_amdgcn_mfma_f32_32x32x16_bf16(af[mt][kk], bfv[nt][kk],
                                                                acc[mt][nt], 0, 0, 0);
  };

  stage(0);                       // tile 0 -> buf0
  for (int kt = 0; kt < 32; kt += 2) {
    __syncthreads();              // tile kt DMA complete (prefetched last iter: drain is cheap)
    stage(1);                     // tile kt+1 -> buf1 (overlaps compute below)
    compute(0);                   // tile kt
    __syncthreads();              // tile kt+1 complete
    if (kt != 30) stage(0);       // tile kt+2 -> buf0
    compute(1);                   // tile kt+1
  }
  __syncthreads();                // all reads done before Tw overlays the buffers

  // ---- epilogue: per-wave 64x64 repack through LDS ----
  unsigned short* Tw = smem + w * 4608;  // 64 * 72
  if (z != 2) {
#pragma unroll
    for (int mt = 0; mt < 2; ++mt)
#pragma unroll
      for (int nt = 0; nt < 2; ++nt) {
        const float bvv = bias[n0 + wc * 64 + nt * 32 + l31];
#pragma unroll
        for (int reg = 0; reg < 16; ++reg) {
          const int rloc = (reg & 3) + 8 * (reg >> 2) + 4 * g;
          float v = acc[mt][nt][reg] + bvv;
          v = v > 0.f ? v : 0.f;
          Tw[(mt * 32 + rloc) * 72 + nt * 32 + l31] = f2bf(v);
        }
      }
    const int row0g = m0 + wr * 64;
    const int colb  = n0 + wc * 64;
#pragma unroll
    for (int i = 0; i < 8; ++i) {
      const int rr = i * 8 + (lane >> 3);
      const int cc = (lane & 7) * 8;
      *(u16x8*)&P[(size_t)(row0g + rr) * 1024 + colb + cc] = *(const u16x8*)&Tw[rr * 72 + cc];
    }
  } else {
    // transposed out (VT[(b*16+h)*64+dh][s]). Tw[col][row]: b64 in (4 consecutive rows/reg-quad).
#pragma unroll
    for (int mt = 0; mt < 2; ++mt)
#pragma unroll
      for (int nt = 0; nt < 2; ++nt) {
        const float bvv = bias[n0 + wc * 64 + nt * 32 + l31];
#pragma unroll
        for (int rq = 0; rq < 4; ++rq) {
          u16x4 pk;
#pragma unroll
          for (int r = 0; r < 4; ++r) {
            float v = acc[mt][nt][rq * 4 + r] + bvv;
            v = v > 0.f ? v : 0.f;
            pk[r] = f2bf(v);
          }
          *(u16x4*)&Tw[(nt * 32 + l31) * 72 + mt * 32 + rq * 8 + g * 4] = pk;
        }
      }
    const int h2 = (n0 >> 6) + wc;        // head index
    const int bb = m0 >> 10;              // batch
    const int s0 = (m0 & 1023) + wr * 64; // s within batch
#pragma unroll
    for (int i = 0; i < 8; ++i) {
      const int rr = i * 8 + (lane >> 3);  // dh
      const int cc = (lane & 7) * 8;       // s chunk
      *(u16x8*)&P[((size_t)(bb * 16 + h2) * 64 + rr) * 1024 + s0 + cc] =
          *(const u16x8*)&Tw[rr * 72 + cc];
    }
  }
}

// ---------------- fused flash attention + mask + residual (unchanged from r6) ----------------
__global__ __launch_bounds__(256) void attn_kernel(
    const unsigned short* __restrict__ QP, const unsigned short* __restrict__ KP,
    const unsigned short* __restrict__ VT, const float* __restrict__ masks,
    const float* __restrict__ query, float* __restrict__ out) {
  __shared__ unsigned short Kt[64 * 64];     // [key][dh], chunk-swizzled, no pad (DMA dest)
  __shared__ unsigned short Vt[64 * 64];     // [dh][key], chunk-swizzled, no pad (DMA dest)
  __shared__ unsigned short Pl[4][32 * 72];  // per-wave P [q][key], padded
  const int tid  = threadIdx.x;
  const int lane = tid & 63;
  const int w    = tid >> 6;
  const int quad = lane >> 4;
  const int l15  = lane & 15;
  const int b = blockIdx.z, h = blockIdx.y;
  const int q0w = blockIdx.x * 128 + w * 32;
  const size_t base = (size_t)b * 1024 * 1024;
  const int bh = b * 16 + h;

  bf16x8 qf[2][2];
#pragma unroll
  for (int mt = 0; mt < 2; ++mt)
#pragma unroll
    for (int kk = 0; kk < 2; ++kk)
      qf[mt][kk] = *(const bf16x8*)&QP[base + (size_t)(q0w + mt * 16 + l15) * 1024 +
                                       h * 64 + kk * 32 + quad * 8];

  f32x4 o[2][4];
  float lsum[2] = {0.f, 0.f};
#pragma unroll
  for (int mt = 0; mt < 2; ++mt)
#pragma unroll
    for (int nd = 0; nd < 4; ++nd) o[mt][nd] = f32x4{0.f, 0.f, 0.f, 0.f};

  const int r_st = lane >> 3;
  const int pc   = lane & 7;
  const int swz  = l15 & 7;
  const float cvt = 0.18033688011112042f;  // (1/sqrt(64)) * log2(e)

  for (int kb = 0; kb < 16; ++kb) {
    const int key0 = kb * 64;
#pragma unroll
    for (int t = 0; t < 2; ++t) {
      const int rowk = (w * 2 + t) * 8 + r_st;
      const int lc   = pc ^ (rowk & 7);
      const unsigned short* gk = &KP[base + (size_t)(key0 + rowk) * 1024 + h * 64 + lc * 8];
      const unsigned short* gv = &VT[((size_t)bh * 64 + rowk) * 1024 + key0 + lc * 8];
      __builtin_amdgcn_global_load_lds((const __attribute__((address_space(1))) void*)gk,
                                       (__attribute__((address_space(3))) void*)&Kt[(w * 2 + t) * 512],
                                       16, 0, 0);
      __builtin_amdgcn_global_load_lds((const __attribute__((address_space(1))) void*)gv,
                                       (__attribute__((address_space(3))) void*)&Vt[(w * 2 + t) * 512],
                                       16, 0, 0);
    }
    __syncthreads();

    bf16x8 kf[2][4];
#pragma unroll
    for (int kk = 0; kk < 2; ++kk)
#pragma unroll
      for (int ni = 0; ni < 4; ++ni)
        kf[kk][ni] = *(const bf16x8*)&Kt[(ni * 16 + l15) * 64 + ((kk * 4 + quad) ^ swz) * 8];

#pragma unroll
    for (int mt = 0; mt < 2; ++mt) {
      f32x4 st[4];
#pragma unroll
      for (int ni = 0; ni < 4; ++ni) st[ni] = f32x4{0.f, 0.f, 0.f, 0.f};
#pragma unroll
      for (int kk = 0; kk < 2; ++kk)
#pragma unroll
        for (int ni = 0; ni < 4; ++ni)
          st[ni] = __builtin_amdgcn_mfma_f32_16x16x32_bf16(kf[kk][ni], qf[mt][kk], st[ni], 0, 0, 0);
      float ls = 0.f;
#pragma unroll
      for (int ni = 0; ni < 4; ++ni) {
        u16x4 pk;
#pragma unroll
        for (int r = 0; r < 4; ++r) {
          const float p = exp2f(st[ni][r] * cvt - 8.0f);  // fixed shift, exact (scores>=0)
          ls += p;
          pk[r] = f2bf(p);
        }
        *(u16x4*)&Pl[w][(mt * 16 + l15) * 72 + ni * 16 + quad * 4] = pk;
      }
      lsum[mt] += ls;
    }

#pragma unroll
    for (int kk = 0; kk < 2; ++kk) {
      bf16x8 pa[2];
#pragma unroll
      for (int mt = 0; mt < 2; ++mt)
        pa[mt] = *(const bf16x8*)&Pl[w][(mt * 16 + l15) * 72 + kk * 32 + quad * 8];
#pragma unroll
      for (int nd = 0; nd < 4; ++nd) {
        bf16x8 vf = *(const bf16x8*)&Vt[(nd * 16 + l15) * 64 + ((kk * 4 + quad) ^ swz) * 8];
#pragma unroll
        for (int mt = 0; mt < 2; ++mt)
          o[mt][nd] = __builtin_amdgcn_mfma_f32_16x16x32_bf16(pa[mt], vf, o[mt][nd], 0, 0, 0);
      }
    }
    __syncthreads();
  }

#pragma unroll
  for (int mt = 0; mt < 2; ++mt) {
    lsum[mt] += __shfl_xor(lsum[mt], 16);
    lsum[mt] += __shfl_xor(lsum[mt], 32);
  }

#pragma unroll
  for (int mt = 0; mt < 2; ++mt)
#pragma unroll
    for (int r = 0; r < 4; ++r) {
      const int rq = quad * 4 + r;
      const float ls = __shfl(lsum[mt], (lane & 48) | rq);
      const int row = q0w + mt * 16 + rq;
      const float scale = masks[b * 1024 + row] / ls;
#pragma unroll
      for (int nd = 0; nd < 4; ++nd) {
        const int col = h * 64 + nd * 16 + l15;
        const size_t gi = base + (size_t)row * 1024 + col;
        out[gi] = o[mt][nd][r] * scale + query[gi];
      }
    }
}

extern "C" void kernel_launch(void* const* d_in, const int* in_sizes, int n_in,
                              void* d_out, int out_size, void* d_ws, size_t ws_size,
                              hipStream_t stream) {
  const float* q     = (const float*)d_in[0];
  const float* k     = (const float*)d_in[1];
  const float* v     = (const float*)d_in[2];
  const float* masks = (const float*)d_in[3];
  const float* Wq    = (const float*)d_in[4];
  const float* bq    = (const float*)d_in[5];
  const float* Wk    = (const float*)d_in[6];
  const float* bk    = (const float*)d_in[7];
  const float* Wv    = (const float*)d_in[8];
  const float* bv    = (const float*)d_in[9];
  float* out = (float*)d_out;
  unsigned short* ws = (unsigned short*)d_ws;

  cvt_kernel<<<dim3(2048, 6), 256, 0, stream>>>(q, k, v, Wq, Wk, Wv, ws);
  proj_gemm<<<dim3(8, 32, 3), 256, 0, stream>>>(ws, bq, bk, bv);
  attn_kernel<<<dim3(8, 16, 4), 256, 0, stream>>>(ws + QP_OFF, ws + KP_OFF, ws + VT_OFF,
                                                  masks, q, out);
}

// Round 9
// 191.584 us; speedup vs baseline: 1.0995x; 1.0366x over previous
//
#include <hip/hip_runtime.h>

// Problem constants: B=4, S=1024, H=1024, NH=16, DH=64, M=B*S=4096.

typedef __attribute__((ext_vector_type(8))) __bf16 bf16x8;
typedef __attribute__((ext_vector_type(4))) float f32x4;
typedef __attribute__((ext_vector_type(16))) float f32x16;
typedef __attribute__((ext_vector_type(8))) unsigned short u16x8;
typedef __attribute__((ext_vector_type(4))) unsigned short u16x4;

// workspace layout (ushort element offsets)
#define XQ_OFF 0u
#define XK_OFF 4194304u
#define XV_OFF 8388608u
#define WQ_OFF 12582912u
#define WK_OFF 13631488u
#define WV_OFF 14680064u
#define QP_OFF 15728640u
#define KP_OFF 19922944u
#define VT_OFF 24117248u   // V projection written DIRECTLY transposed: [(b*16+h)*64+dh][s]
// total = 28311552 ushorts = 54 MiB

__device__ __forceinline__ unsigned short f2bf(float f) {
  union { float f; unsigned int u; } c; c.f = f;
  return (unsigned short)((c.u + 0x7fffu + ((c.u >> 16) & 1u)) >> 16);  // RNE
}

// ---------------- fp32 -> bf16 conversion of inputs ----------------
__global__ __launch_bounds__(256) void cvt_kernel(
    const float* __restrict__ q, const float* __restrict__ k, const float* __restrict__ v,
    const float* __restrict__ wq, const float* __restrict__ wk, const float* __restrict__ wv,
    unsigned short* __restrict__ ws) {
  const int z = blockIdx.y;
  const float* src; unsigned short* dst; int n;
  switch (z) {
    case 0: src = q;  dst = ws + XQ_OFF; n = 4194304; break;
    case 1: src = k;  dst = ws + XK_OFF; n = 4194304; break;
    case 2: src = v;  dst = ws + XV_OFF; n = 4194304; break;
    case 3: src = wq; dst = ws + WQ_OFF; n = 1048576; break;
    case 4: src = wk; dst = ws + WK_OFF; n = 1048576; break;
    default: src = wv; dst = ws + WV_OFF; n = 1048576; break;
  }
  const int i8 = (blockIdx.x * 256 + threadIdx.x) * 8;
  if (i8 >= n) return;
  const float4 f0 = *(const float4*)(src + i8);
  const float4 f1 = *(const float4*)(src + i8 + 4);
  u16x8 r;
  r[0] = f2bf(f0.x); r[1] = f2bf(f0.y); r[2] = f2bf(f0.z); r[3] = f2bf(f0.w);
  r[4] = f2bf(f1.x); r[5] = f2bf(f1.y); r[6] = f2bf(f1.z); r[7] = f2bf(f1.w);
  *(u16x8*)(dst + i8) = r;
}

// ---------------- fused projection GEMMs (r8 version, unchanged) ----------------
__global__ __launch_bounds__(256) void proj_gemm(
    unsigned short* __restrict__ ws,
    const float* __restrict__ bq, const float* __restrict__ bk, const float* __restrict__ bv) {
  __shared__ unsigned short smem[18432];  // buf0: As[0:4096]+Bs[4096:8192]; buf1: +8192; Tw overlays
  const int z = blockIdx.z;
  const unsigned short* X = ws + (z == 0 ? XQ_OFF : z == 1 ? XK_OFF : XV_OFF);
  const unsigned short* W = ws + (z == 0 ? WQ_OFF : z == 1 ? WK_OFF : WV_OFF);
  unsigned short* P = ws + (z == 0 ? QP_OFF : z == 1 ? KP_OFF : VT_OFF);
  const float* bias = z == 0 ? bq : z == 1 ? bk : bv;

  const int tid  = threadIdx.x;
  const int lane = tid & 63;
  const int w    = tid >> 6;
  const int l31  = lane & 31;
  const int g    = lane >> 5;
  const int wr = w >> 1, wc = w & 1;

  // XCD-aware remap: XCD j (lin%8) gets m-tiles 4j..4j+3 x all 8 n-tiles (3MB < 4MB L2).
  const int lin = blockIdx.x + 8 * blockIdx.y;   // 0..255
  const int xcd = lin & 7;
  const int idx = lin >> 3;                      // 0..31
  const int m0 = (xcd * 4 + (idx >> 3)) * 128;
  const int n0 = (idx & 7) * 128;

  f32x16 acc[2][2];
#pragma unroll
  for (int i = 0; i < 2; ++i)
#pragma unroll
    for (int j = 0; j < 2; ++j)
#pragma unroll
      for (int r = 0; r < 16; ++r) acc[i][j][r] = 0.f;

  const int c1 = 256 + tid;
  const int row0 = tid >> 2, kc0 = (((tid & 3) ^ (row0 & 3)) * 8);
  const int row1 = c1 >> 2,  kc1 = (((c1 & 3) ^ (row1 & 3)) * 8);
  const unsigned short* gA0 = X + (size_t)(m0 + row0) * 1024 + kc0;
  const unsigned short* gA1 = X + (size_t)(m0 + row1) * 1024 + kc1;
  const unsigned short* gB0 = W + (size_t)(n0 + row0) * 1024 + kc0;
  const unsigned short* gB1 = W + (size_t)(n0 + row1) * 1024 + kc1;
  const int d0 = w * 512, d1 = 2048 + w * 512;

  auto stage = [&](int buf) {
    unsigned short* Ab = smem + buf * 8192;
    unsigned short* Bb = Ab + 4096;
    __builtin_amdgcn_global_load_lds((const __attribute__((address_space(1))) void*)gA0,
                                     (__attribute__((address_space(3))) void*)(Ab + d0), 16, 0, 0);
    __builtin_amdgcn_global_load_lds((const __attribute__((address_space(1))) void*)gB0,
                                     (__attribute__((address_space(3))) void*)(Bb + d0), 16, 0, 0);
    __builtin_amdgcn_global_load_lds((const __attribute__((address_space(1))) void*)gA1,
                                     (__attribute__((address_space(3))) void*)(Ab + d1), 16, 0, 0);
    __builtin_amdgcn_global_load_lds((const __attribute__((address_space(1))) void*)gB1,
                                     (__attribute__((address_space(3))) void*)(Bb + d1), 16, 0, 0);
    gA0 += 32; gA1 += 32; gB0 += 32; gB1 += 32;
  };
  auto compute = [&](int buf) {
    const unsigned short* Ab = smem + buf * 8192;
    const unsigned short* Bb = Ab + 4096;
    bf16x8 af[2][2], bfv[2][2];
#pragma unroll
    for (int mt = 0; mt < 2; ++mt)
#pragma unroll
      for (int kk = 0; kk < 2; ++kk) {
        const int ra = wr * 64 + mt * 32 + l31;
        af[mt][kk] = *(const bf16x8*)&Ab[ra * 32 + (((kk * 2 + g) ^ (ra & 3)) * 8)];
      }
#pragma unroll
    for (int nt = 0; nt < 2; ++nt)
#pragma unroll
      for (int kk = 0; kk < 2; ++kk) {
        const int rb = wc * 64 + nt * 32 + l31;
        bfv[nt][kk] = *(const bf16x8*)&Bb[rb * 32 + (((kk * 2 + g) ^ (rb & 3)) * 8)];
      }
#pragma unroll
    for (int mt = 0; mt < 2; ++mt)
#pragma unroll
      for (int nt = 0; nt < 2; ++nt)
#pragma unroll
        for (int kk = 0; kk < 2; ++kk)
          acc[mt][nt] = __builtin_amdgcn_mfma_f32_32x32x16_bf16(af[mt][kk], bfv[nt][kk],
                                                                acc[mt][nt], 0, 0, 0);
  };

  stage(0);
  for (int kt = 0; kt < 32; kt += 2) {
    __syncthreads();
    stage(1);
    compute(0);
    __syncthreads();
    if (kt != 30) stage(0);
    compute(1);
  }
  __syncthreads();

  unsigned short* Tw = smem + w * 4608;  // 64 * 72
  if (z != 2) {
#pragma unroll
    for (int mt = 0; mt < 2; ++mt)
#pragma unroll
      for (int nt = 0; nt < 2; ++nt) {
        const float bvv = bias[n0 + wc * 64 + nt * 32 + l31];
#pragma unroll
        for (int reg = 0; reg < 16; ++reg) {
          const int rloc = (reg & 3) + 8 * (reg >> 2) + 4 * g;
          float v = acc[mt][nt][reg] + bvv;
          v = v > 0.f ? v : 0.f;
          Tw[(mt * 32 + rloc) * 72 + nt * 32 + l31] = f2bf(v);
        }
      }
    const int row0g = m0 + wr * 64;
    const int colb  = n0 + wc * 64;
#pragma unroll
    for (int i = 0; i < 8; ++i) {
      const int rr = i * 8 + (lane >> 3);
      const int cc = (lane & 7) * 8;
      *(u16x8*)&P[(size_t)(row0g + rr) * 1024 + colb + cc] = *(const u16x8*)&Tw[rr * 72 + cc];
    }
  } else {
#pragma unroll
    for (int mt = 0; mt < 2; ++mt)
#pragma unroll
      for (int nt = 0; nt < 2; ++nt) {
        const float bvv = bias[n0 + wc * 64 + nt * 32 + l31];
#pragma unroll
        for (int rq = 0; rq < 4; ++rq) {
          u16x4 pk;
#pragma unroll
          for (int r = 0; r < 4; ++r) {
            float v = acc[mt][nt][rq * 4 + r] + bvv;
            v = v > 0.f ? v : 0.f;
            pk[r] = f2bf(v);
          }
          *(u16x4*)&Tw[(nt * 32 + l31) * 72 + mt * 32 + rq * 8 + g * 4] = pk;
        }
      }
    const int h2 = (n0 >> 6) + wc;
    const int bb = m0 >> 10;
    const int s0 = (m0 & 1023) + wr * 64;
#pragma unroll
    for (int i = 0; i < 8; ++i) {
      const int rr = i * 8 + (lane >> 3);
      const int cc = (lane & 7) * 8;
      *(u16x8*)&P[((size_t)(bb * 16 + h2) * 64 + rr) * 1024 + s0 + cc] =
          *(const u16x8*)&Tw[rr * 72 + cc];
    }
  }
}

// ---------------- fused flash attention + mask + residual ----------------
// r9: grid (64, 8): x = bh (so lin%8 = bh%8 -> all 8 q-blocks of one (b,h) share an XCD;
// per-XCD K/V set 2MB fits L2), y = q-block. DOUBLE-BUFFERED K/V staging (prefetch kb+1
// before computing kb; 1 barrier/iter — r8's proj lesson applied). Softmax pack uses
// round-half-up + shift/mask pair-pack (folds to v_perm) instead of the 4-inst RNE.
__global__ __launch_bounds__(256) void attn_kernel(
    const unsigned short* __restrict__ QP, const unsigned short* __restrict__ KP,
    const unsigned short* __restrict__ VT, const float* __restrict__ masks,
    const float* __restrict__ query, float* __restrict__ out) {
  __shared__ unsigned short Kt[2][64 * 64];  // [key][dh], chunk-swizzled, no pad (DMA dest)
  __shared__ unsigned short Vt[2][64 * 64];  // [dh][key], chunk-swizzled, no pad (DMA dest)
  __shared__ unsigned short Pl[4][32 * 72];  // per-wave P [q][key], padded
  const int tid  = threadIdx.x;
  const int lane = tid & 63;
  const int w    = tid >> 6;
  const int quad = lane >> 4;
  const int l15  = lane & 15;
  const int bh = blockIdx.x;                 // b*16 + h
  const int b = bh >> 4, h = bh & 15;
  const int q0w = blockIdx.y * 128 + w * 32;
  const size_t base = (size_t)b * 1024 * 1024;

  bf16x8 qf[2][2];
#pragma unroll
  for (int mt = 0; mt < 2; ++mt)
#pragma unroll
    for (int kk = 0; kk < 2; ++kk)
      qf[mt][kk] = *(const bf16x8*)&QP[base + (size_t)(q0w + mt * 16 + l15) * 1024 +
                                       h * 64 + kk * 32 + quad * 8];

  f32x4 o[2][4];
  float lsum[2] = {0.f, 0.f};
#pragma unroll
  for (int mt = 0; mt < 2; ++mt)
#pragma unroll
    for (int nd = 0; nd < 4; ++nd) o[mt][nd] = f32x4{0.f, 0.f, 0.f, 0.f};

  const int r_st = lane >> 3;
  const int pc   = lane & 7;
  const int swz  = l15 & 7;
  const float cvt = 0.18033688011112042f;  // (1/sqrt(64)) * log2(e)

  auto stage = [&](int key0, int buf) {
#pragma unroll
    for (int t = 0; t < 2; ++t) {
      const int rowk = (w * 2 + t) * 8 + r_st;
      const int lc   = pc ^ (rowk & 7);
      const unsigned short* gk = &KP[base + (size_t)(key0 + rowk) * 1024 + h * 64 + lc * 8];
      const unsigned short* gv = &VT[((size_t)bh * 64 + rowk) * 1024 + key0 + lc * 8];
      __builtin_amdgcn_global_load_lds((const __attribute__((address_space(1))) void*)gk,
                                       (__attribute__((address_space(3))) void*)&Kt[buf][(w * 2 + t) * 512],
                                       16, 0, 0);
      __builtin_amdgcn_global_load_lds((const __attribute__((address_space(1))) void*)gv,
                                       (__attribute__((address_space(3))) void*)&Vt[buf][(w * 2 + t) * 512],
                                       16, 0, 0);
    }
  };

  stage(0, 0);
  for (int kb = 0; kb < 16; ++kb) {
    __syncthreads();                       // buf[kb&1] DMA drained (full iter in flight)
    if (kb < 15) stage((kb + 1) * 64, (kb + 1) & 1);
    const unsigned short* Ktb = Kt[kb & 1];
    const unsigned short* Vtb = Vt[kb & 1];

    bf16x8 kf[2][4];
#pragma unroll
    for (int kk = 0; kk < 2; ++kk)
#pragma unroll
      for (int ni = 0; ni < 4; ++ni)
        kf[kk][ni] = *(const bf16x8*)&Ktb[(ni * 16 + l15) * 64 + ((kk * 4 + quad) ^ swz) * 8];

    // S^T = K.Q^T per m-subtile; C-layout: row=key=quad*4+reg(+16ni), col=q=l15
#pragma unroll
    for (int mt = 0; mt < 2; ++mt) {
      f32x4 st[4];
#pragma unroll
      for (int ni = 0; ni < 4; ++ni) st[ni] = f32x4{0.f, 0.f, 0.f, 0.f};
#pragma unroll
      for (int kk = 0; kk < 2; ++kk)
#pragma unroll
        for (int ni = 0; ni < 4; ++ni)
          st[ni] = __builtin_amdgcn_mfma_f32_16x16x32_bf16(kf[kk][ni], qf[mt][kk], st[ni], 0, 0, 0);
      float ls = 0.f;
#pragma unroll
      for (int ni = 0; ni < 4; ++ni) {
        float p0 = exp2f(fmaf(st[ni][0], cvt, -8.0f));  // fixed shift, exact (scores>=0)
        float p1 = exp2f(fmaf(st[ni][1], cvt, -8.0f));
        float p2 = exp2f(fmaf(st[ni][2], cvt, -8.0f));
        float p3 = exp2f(fmaf(st[ni][3], cvt, -8.0f));
        ls += (p0 + p1) + (p2 + p3);
        const unsigned int u0 = __float_as_uint(p0) + 0x8000u;  // round-half-up to bf16
        const unsigned int u1 = __float_as_uint(p1) + 0x8000u;
        const unsigned int u2 = __float_as_uint(p2) + 0x8000u;
        const unsigned int u3 = __float_as_uint(p3) + 0x8000u;
        uint2 pk;
        pk.x = (u0 >> 16) | (u1 & 0xffff0000u);  // folds to v_perm_b32
        pk.y = (u2 >> 16) | (u3 & 0xffff0000u);
        *(uint2*)&Pl[w][(mt * 16 + l15) * 72 + ni * 16 + quad * 4] = pk;
      }
      lsum[mt] += ls;
    }

    // O += P.V : pa (A) from Pl, vf (B) from swizzled Vt
#pragma unroll
    for (int kk = 0; kk < 2; ++kk) {
      bf16x8 pa[2];
#pragma unroll
      for (int mt = 0; mt < 2; ++mt)
        pa[mt] = *(const bf16x8*)&Pl[w][(mt * 16 + l15) * 72 + kk * 32 + quad * 8];
#pragma unroll
      for (int nd = 0; nd < 4; ++nd) {
        bf16x8 vf = *(const bf16x8*)&Vtb[(nd * 16 + l15) * 64 + ((kk * 4 + quad) ^ swz) * 8];
#pragma unroll
        for (int mt = 0; mt < 2; ++mt)
          o[mt][nd] = __builtin_amdgcn_mfma_f32_16x16x32_bf16(pa[mt], vf, o[mt][nd], 0, 0, 0);
      }
    }
  }

  // reduce lsum across quads (lanes l15 hold q=l15 partials in all 4 quads)
#pragma unroll
  for (int mt = 0; mt < 2; ++mt) {
    lsum[mt] += __shfl_xor(lsum[mt], 16);
    lsum[mt] += __shfl_xor(lsum[mt], 32);
  }

  // epilogue: out = mask[q] * O / l + query
#pragma unroll
  for (int mt = 0; mt < 2; ++mt)
#pragma unroll
    for (int r = 0; r < 4; ++r) {
      const int rq = quad * 4 + r;
      const float ls = __shfl(lsum[mt], (lane & 48) | rq);
      const int row = q0w + mt * 16 + rq;
      const float scale = masks[b * 1024 + row] / ls;
#pragma unroll
      for (int nd = 0; nd < 4; ++nd) {
        const int col = h * 64 + nd * 16 + l15;
        const size_t gi = base + (size_t)row * 1024 + col;
        out[gi] = o[mt][nd][r] * scale + query[gi];
      }
    }
}

extern "C" void kernel_launch(void* const* d_in, const int* in_sizes, int n_in,
                              void* d_out, int out_size, void* d_ws, size_t ws_size,
                              hipStream_t stream) {
  const float* q     = (const float*)d_in[0];
  const float* k     = (const float*)d_in[1];
  const float* v     = (const float*)d_in[2];
  const float* masks = (const float*)d_in[3];
  const float* Wq    = (const float*)d_in[4];
  const float* bq    = (const float*)d_in[5];
  const float* Wk    = (const float*)d_in[6];
  const float* bk    = (const float*)d_in[7];
  const float* Wv    = (const float*)d_in[8];
  const float* bv    = (const float*)d_in[9];
  float* out = (float*)d_out;
  unsigned short* ws = (unsigned short*)d_ws;

  cvt_kernel<<<dim3(2048, 6), 256, 0, stream>>>(q, k, v, Wq, Wk, Wv, ws);
  proj_gemm<<<dim3(8, 32, 3), 256, 0, stream>>>(ws, bq, bk, bv);
  attn_kernel<<<dim3(64, 8), 256, 0, stream>>>(ws + QP_OFF, ws + KP_OFF, ws + VT_OFF,
                                               masks, q, out);
}